// Round 8
// baseline (304.125 us; speedup 1.0000x reference)
//
#include <hip/hip_runtime.h>

// LightGCN encoder on MI355X — round 8.
// (1) Persistent-wave pull: 8192 waves (100% occupancy), each owning ~19
//     consecutive nodes, nodeinfo prefetched one node ahead -> cross-node
//     latency overlap; sequential packed/index/store streams per wave.
// (2) init_g0 fused into build_csr (bucket block knows its nodes' degrees
//     in LDS) -> one fewer dispatch. 6 dispatches total.
#define N_USERS 100000
#define N_NODES 150000
#define DIM 64
#define BATCH 4096
#define BSHIFT 9
#define BUCKET 512
#define NB 293                 // ceil(150000 / 512) buckets
#define PAIRS_PER_BLK 8192     // undirected pairs per binning block
#define CAPSHIFT 14
#define CAP (1 << CAPSHIFT)    // slots per bucket region (max ~10.8K used)
#define PULL_BLOCKS 2048
#define PULL_CHUNK 19          // ceil(N_NODES / 8192 waves)

typedef unsigned short bf16_t;

static __device__ __forceinline__ float bf2f(bf16_t h) {
    return __uint_as_float(((unsigned)h) << 16);
}
static __device__ __forceinline__ bf16_t f2bf(float f) {  // round-nearest-even
    unsigned u = __float_as_uint(f);
    return (bf16_t)((u + 0x7FFFu + ((u >> 16) & 1u)) >> 16);
}

// --- Fused binning: LDS hist -> range reservation -> scatter ---------------
// cursor[] must be zeroed before launch. binned word = (local_dst[9b]<<18)|src.
__global__ void lgcn_bin(const int* __restrict__ row, const int* __restrict__ col,
                         int* __restrict__ cursor, int* __restrict__ binned, int EH) {
    __shared__ int h[4 * NB];
    __shared__ int basecur[NB];
    for (int i = threadIdx.x; i < 4 * NB; i += blockDim.x) h[i] = 0;
    __syncthreads();
    int k = blockIdx.x;
    int wv = threadIdx.x >> 6;
    int* hw = h + wv * NB;
    int e0 = k * PAIRS_PER_BLK;
    int e1 = min(EH, e0 + PAIRS_PER_BLK);
    int nq = (e1 - e0) >> 2;                     // both multiples of 4
    const int4* r4 = (const int4*)(row + e0);
    const int4* c4 = (const int4*)(col + e0);
    for (int q = threadIdx.x; q < nq; q += blockDim.x) {
        int4 r = r4[q];
        int4 c = c4[q];
        atomicAdd(&hw[r.x >> BSHIFT], 1); atomicAdd(&hw[c.x >> BSHIFT], 1);
        atomicAdd(&hw[r.y >> BSHIFT], 1); atomicAdd(&hw[c.y >> BSHIFT], 1);
        atomicAdd(&hw[r.z >> BSHIFT], 1); atomicAdd(&hw[c.z >> BSHIFT], 1);
        atomicAdd(&hw[r.w >> BSHIFT], 1); atomicAdd(&hw[c.w >> BSHIFT], 1);
    }
    __syncthreads();
    for (int i = threadIdx.x; i < NB; i += blockDim.x) {
        int tot = h[i] + h[NB + i] + h[2 * NB + i] + h[3 * NB + i];
        int base = i << CAPSHIFT;
        if (tot) base += atomicAdd(&cursor[i], tot);   // reserve range
        basecur[i] = base;
    }
    __syncthreads();
    for (int q = threadIdx.x; q < nq; q += blockDim.x) {
        int4 r = r4[q];
        int4 c = c4[q];
        int rr[4] = { r.x, r.y, r.z, r.w };
        int cc[4] = { c.x, c.y, c.z, c.w };
#pragma unroll
        for (int j = 0; j < 4; ++j) {
            int p1 = atomicAdd(&basecur[cc[j] >> BSHIFT], 1);  // LDS atomic
            binned[p1] = ((cc[j] & (BUCKET - 1)) << 18) | rr[j];
            int p2 = atomicAdd(&basecur[rr[j] >> BSHIFT], 1);
            binned[p2] = ((rr[j] & (BUCKET - 1)) << 18) | cc[j];
        }
    }
}

// --- Per-bucket padded CSR + fused g0 emission -----------------------------
// Node segments padded to multiple of 4; pad slots = N_NODES (zero row).
// nodeinfo = {start, deg, bits(1/sqrt(da)), bits(sqrt(da))}.
// Also writes g0[n] = norm[n]*x[n] (bf16) for this bucket's nodes, and the
// zero row N_NODES into both feature buffers.
__global__ void __launch_bounds__(BUCKET)
lgcn_build_csr(const int* __restrict__ cursor, const int* __restrict__ binned,
               int4* __restrict__ nodeinfo, int* __restrict__ packed,
               const float* __restrict__ ue, const float* __restrict__ ie,
               bf16_t* __restrict__ g0, bf16_t* __restrict__ gz) {
    __shared__ int hist[BUCKET], sA[BUCKET], sB[BUCKET], cur[BUCKET];
    int b = blockIdx.x;
    int tid = threadIdx.x;
    hist[tid] = 0;
    __syncthreads();
    int e0 = b << CAPSHIFT;
    int e1 = e0 + cursor[b];                   // bucket edge count
    for (int j = e0 + tid; j < e1; j += BUCKET)
        atomicAdd(&hist[binned[j] >> 18], 1);
    __syncthreads();
    int deg = hist[tid];
    int degp = (deg + 3) & ~3;                 // padded segment length
    sA[tid] = degp;
    __syncthreads();
    int* c_ = sA; int* n_ = sB;
    for (int off = 1; off < BUCKET; off <<= 1) {
        n_[tid] = (tid >= off) ? c_[tid] + c_[tid - off] : c_[tid];
        __syncthreads();
        int* t = c_; c_ = n_; n_ = t;
    }
    int start = e0 + (c_[tid] - degp);         // exclusive scan, int4-aligned
    cur[tid] = start;
    int node = (b << BSHIFT) + tid;
    if (node < N_NODES) {
        float da = (deg == 0) ? 1.0f : (float)deg;
        float sq = sqrtf(da);
        int4 ni;
        ni.x = start;
        ni.y = deg;
        ni.z = __float_as_int(1.0f / sq);
        ni.w = __float_as_int(sq);
        nodeinfo[node] = ni;
    }
    __syncthreads();
    // CSR scatter (LDS cursors; hist[] stays intact for the g0 phase).
    for (int j = e0 + tid; j < e1; j += BUCKET) {
        int w = binned[j];
        int pos = atomicAdd(&cur[w >> 18], 1); // LDS atomic
        packed[pos] = w & 0x3FFFF;             // src only
    }
    // Pad slots -> zero row (disjoint targets; no sync needed).
    for (int kk = deg; kk < degp; ++kk)
        packed[start + kk] = N_NODES;
    // Fused g0: 512 nodes x 16 ushort4 chunks, coalesced.
    const int nodeBase = b << BSHIFT;
#pragma unroll
    for (int k = 0; k < 16; ++k) {
        int slot = k * BUCKET + tid;           // [0, 8192)
        int nl = slot >> 4;                    // local node in bucket
        int cc = slot & 15;
        int n = nodeBase + nl;
        if (n > N_NODES) continue;
        if (n == N_NODES) {                    // zero row in BOTH buffers
            ((ushort4*)(g0 + (size_t)N_NODES * DIM))[cc] = make_ushort4(0, 0, 0, 0);
            ((ushort4*)(gz + (size_t)N_NODES * DIM))[cc] = make_ushort4(0, 0, 0, 0);
            continue;
        }
        int dg = hist[nl];
        float da = (dg == 0) ? 1.0f : (float)dg;
        float nm = 1.0f / sqrtf(da);
        float4 x = (n < N_USERS)
                 ? ((const float4*)ue)[(size_t)n * (DIM / 4) + cc]
                 : ((const float4*)ie)[(size_t)(n - N_USERS) * (DIM / 4) + cc];
        ushort4 o;
        o.x = f2bf(x.x * nm); o.y = f2bf(x.y * nm);
        o.z = f2bf(x.z * nm); o.w = f2bf(x.w * nm);
        ((ushort4*)(g0 + (size_t)n * DIM))[cc] = o;
    }
}

// --- Propagation -----------------------------------------------------------

// Gather core: 16-lane group sums g rows for edges [start, start+deg).
// Pad slots point at the zero row -> plain adds, no clamps, no weights.
static __device__ __forceinline__ float4
gather_sum(const bf16_t* __restrict__ g, const int* __restrict__ packed,
           int start, int deg, int grp, int c) {
    float4 acc = make_float4(0.f, 0.f, 0.f, 0.f);
    for (int o = 4 * grp; o < deg; o += 16) {
        int4 e4 = *(const int4*)(packed + start + o);  // 16-B aligned
        ushort4 v0 = ((const ushort4*)(g + (size_t)e4.x * DIM))[c];
        ushort4 v1 = ((const ushort4*)(g + (size_t)e4.y * DIM))[c];
        ushort4 v2 = ((const ushort4*)(g + (size_t)e4.z * DIM))[c];
        ushort4 v3 = ((const ushort4*)(g + (size_t)e4.w * DIM))[c];
        acc.x += bf2f(v0.x); acc.y += bf2f(v0.y);
        acc.z += bf2f(v0.z); acc.w += bf2f(v0.w);
        acc.x += bf2f(v1.x); acc.y += bf2f(v1.y);
        acc.z += bf2f(v1.z); acc.w += bf2f(v1.w);
        acc.x += bf2f(v2.x); acc.y += bf2f(v2.y);
        acc.z += bf2f(v2.z); acc.w += bf2f(v2.w);
        acc.x += bf2f(v3.x); acc.y += bf2f(v3.y);
        acc.z += bf2f(v3.z); acc.w += bf2f(v3.w);
    }
    return acc;
}

// Persistent-wave full pull: each wave owns PULL_CHUNK consecutive nodes;
// next node's nodeinfo is prefetched before gathering the current one.
// gn[n] = bf16( norm[n]^2 * sum_{s in N(n)} g[s] ).
__global__ void __launch_bounds__(256)
lgcn_pull(const bf16_t* __restrict__ g, const int4* __restrict__ nodeinfo,
          const int* __restrict__ packed, bf16_t* __restrict__ gn) {
    int wid = (blockIdx.x << 2) + (threadIdx.x >> 6);
    int lane = threadIdx.x & 63;
    int grp = lane >> 4;
    int c = lane & 15;
    int n0 = wid * PULL_CHUNK;
    int n1 = min(N_NODES, n0 + PULL_CHUNK);
    if (n0 >= n1) return;
    int4 ni = nodeinfo[n0];
    for (int n = n0; n < n1; ++n) {
        int4 nin = (n + 1 < n1) ? nodeinfo[n + 1] : ni;   // prefetch next
        float4 acc = gather_sum(g, packed, ni.x, ni.y, grp, c);
#pragma unroll
        for (int off = 16; off < 64; off <<= 1) {
            acc.x += __shfl_xor(acc.x, off, 64);
            acc.y += __shfl_xor(acc.y, off, 64);
            acc.z += __shfl_xor(acc.z, off, 64);
            acc.w += __shfl_xor(acc.w, off, 64);
        }
        if (lane < 16) {
            float nm = __int_as_float(ni.z);
            float s2 = nm * nm;
            ushort4 o;
            o.x = f2bf(acc.x * s2); o.y = f2bf(acc.y * s2);
            o.z = f2bf(acc.z * s2); o.w = f2bf(acc.w * s2);
            ((ushort4*)(gn + (size_t)n * DIM))[c] = o;
        }
        ni = nin;
    }
}

// Fused layer-3 + epilogue, batch nodes only:
// out[slot] = 0.25*( x[n] + rn*g1[n] + rn*g2[n] + nm*sum_{s in N(n)} g2[s] ).
__global__ void __launch_bounds__(256)
lgcn_final(const float* __restrict__ ue, const float* __restrict__ ie,
           const bf16_t* __restrict__ g1, const bf16_t* __restrict__ g2,
           const int4* __restrict__ nodeinfo, const int* __restrict__ packed,
           const int* __restrict__ uid, const int* __restrict__ iid,
           float* __restrict__ out) {
    int slot = blockIdx.x * 4 + (threadIdx.x >> 6);
    if (slot >= 2 * BATCH) return;
    int lane = threadIdx.x & 63;
    int grp = lane >> 4;
    int c = lane & 15;
    int isItem = slot >= BATCH;
    int b = isItem ? (slot - BATCH) : slot;
    int node = isItem ? (N_USERS + iid[b]) : uid[b];
    int4 ni = nodeinfo[node];
    float4 acc = gather_sum(g2, packed, ni.x, ni.y, grp, c);
#pragma unroll
    for (int off = 16; off < 64; off <<= 1) {
        acc.x += __shfl_xor(acc.x, off, 64);
        acc.y += __shfl_xor(acc.y, off, 64);
        acc.z += __shfl_xor(acc.z, off, 64);
        acc.w += __shfl_xor(acc.w, off, 64);
    }
    if (lane < 16) {
        const float* xb = isItem ? (ie + (size_t)(node - N_USERS) * DIM)
                                 : (ue + (size_t)node * DIM);
        float4 x = ((const float4*)xb)[c];
        ushort4 a1 = ((const ushort4*)(g1 + (size_t)node * DIM))[c];
        ushort4 a2 = ((const ushort4*)(g2 + (size_t)node * DIM))[c];
        float rn = __int_as_float(ni.w);
        float nm = __int_as_float(ni.z);
        float4 r;
        r.x = 0.25f * (x.x + rn * (bf2f(a1.x) + bf2f(a2.x)) + nm * acc.x);
        r.y = 0.25f * (x.y + rn * (bf2f(a1.y) + bf2f(a2.y)) + nm * acc.y);
        r.z = 0.25f * (x.z + rn * (bf2f(a1.z) + bf2f(a2.z)) + nm * acc.z);
        r.w = 0.25f * (x.w + rn * (bf2f(a1.w) + bf2f(a2.w)) + nm * acc.w);
        ((float4*)(out + (size_t)slot * DIM))[c] = r;
    }
}

// --- Launch ----------------------------------------------------------------

extern "C" void kernel_launch(void* const* d_in, const int* in_sizes, int n_in,
                              void* d_out, int out_size, void* d_ws, size_t ws_size,
                              hipStream_t stream) {
    const float* ue  = (const float*)d_in[0];
    const float* ie  = (const float*)d_in[1];
    const int*   ei  = (const int*)d_in[3];
    const int*   uid = (const int*)d_in[4];
    const int*   iid = (const int*)d_in[5];
    float* out = (float*)d_out;

    const int E  = in_sizes[2];     // 2,000,000 directed edges
    const int EH = E / 2;           // 1,000,000 undirected pairs
    const int* row = ei;            // first-half src = user ids
    const int* col = ei + E;        // first-half dst = item node ids

    const int NB1 = (EH + PAIRS_PER_BLK - 1) / PAIRS_PER_BLK;   // 123

    // Workspace carve-up (256-B aligned), ~80 MB total.
    char* p = (char*)d_ws;
    size_t off = 0;
    auto carve = [&](size_t bytes) -> char* {
        char* r = p + off;
        off += (bytes + 255) & ~(size_t)255;
        return r;
    };
    const size_t nodeBf16 = (size_t)(N_NODES + 1) * DIM * sizeof(bf16_t); // +zero row
    bf16_t* gA       = (bf16_t*)carve(nodeBf16);
    bf16_t* gB       = (bf16_t*)carve(nodeBf16);
    int4*   nodeinfo = (int4*)carve((size_t)N_NODES * sizeof(int4));     // 2.4 MB
    int*    cursor   = (int*)carve((size_t)NB * sizeof(int));
    int*    binned   = (int*)carve((size_t)NB * CAP * sizeof(int));      // 19.2 MB
    int*    packed   = (int*)carve((size_t)NB * CAP * sizeof(int));      // 19.2 MB
    (void)ws_size;

    // 1) Binning (cursor must start at zero) + per-bucket CSR (+g0 fused).
    hipMemsetAsync(cursor, 0, (size_t)NB * sizeof(int), stream);
    lgcn_bin<<<NB1, 256, 0, stream>>>(row, col, cursor, binned, EH);
    lgcn_build_csr<<<NB, BUCKET, 0, stream>>>(cursor, binned, nodeinfo, packed,
                                              ue, ie, gA, gB);

    // 2) Two persistent-wave pulls (g1, g2), then fused batch layer 3 + epilogue.
    lgcn_pull<<<PULL_BLOCKS, 256, 0, stream>>>(gA, nodeinfo, packed, gB);  // g1
    lgcn_pull<<<PULL_BLOCKS, 256, 0, stream>>>(gB, nodeinfo, packed, gA);  // g2
    lgcn_final<<<(2 * BATCH + 3) / 4, 256, 0, stream>>>(
        ue, ie, gB, gA, nodeinfo, packed, uid, iid, out);
}

// Round 9
// 239.321 us; speedup vs baseline: 1.2708x; 1.2708x over previous
//
#include <hip/hip_runtime.h>

// LightGCN encoder on MI355X — round 9.
// Revert round-8 persistent pull (regressed: WRITE_SIZE 19->89 MB, occ 53%).
// Pull/build/init/final = round-7 form (proven 238.5 us). New: lgcn_bin
// stages each block's edges bucket-sorted in LDS and drains with coalesced
// writes — kills the 2M scattered single-dword global stores.
#define N_USERS 100000
#define N_NODES 150000
#define DIM 64
#define BATCH 4096
#define BSHIFT 9
#define BUCKET 512
#define NB 293                 // ceil(150000 / 512) buckets
#define PAIRS_PER_BLK 2048     // undirected pairs per binning block
#define EDGES_PER_BLK (2 * PAIRS_PER_BLK)
#define CAPSHIFT 14
#define CAP (1 << CAPSHIFT)    // slots per bucket region (max ~10.9K used)

typedef unsigned short bf16_t;

static __device__ __forceinline__ float bf2f(bf16_t h) {
    return __uint_as_float(((unsigned)h) << 16);
}
static __device__ __forceinline__ bf16_t f2bf(float f) {  // round-nearest-even
    unsigned u = __float_as_uint(f);
    return (bf16_t)((u + 0x7FFFu + ((u >> 16) & 1u)) >> 16);
}

// --- Binning with LDS bucket-sort + coalesced drain ------------------------
// cursor[] must be zeroed. binned word = (local_dst[9b]<<18)|src.
__global__ void __launch_bounds__(256)
lgcn_bin(const int* __restrict__ row, const int* __restrict__ col,
         int* __restrict__ cursor, int* __restrict__ binned, int EH) {
    __shared__ int h[4 * NB];             // per-wave sub-hists
    __shared__ int sA[512], sB[512];      // scan ping-pong
    __shared__ int gb[NB];                // global run base per bucket
    __shared__ int lo[NB];                // local run offset (exclusive)
    __shared__ int lc[NB];                // scatter cursors
    __shared__ int2 stage[EDGES_PER_BLK]; // {gaddr, word}, 32 KB

    int tid = threadIdx.x;
    for (int i = tid; i < 4 * NB; i += 256) h[i] = 0;
    __syncthreads();
    int k = blockIdx.x;
    int e0 = k * PAIRS_PER_BLK;
    int e1 = min(EH, e0 + PAIRS_PER_BLK);
    int nq = (e1 - e0) >> 2;              // pair counts are multiples of 4
    const int4* r4 = (const int4*)(row + e0);
    const int4* c4 = (const int4*)(col + e0);
    int wv = tid >> 6;
    int* hw = h + wv * NB;
    // A: per-wave histograms.
    for (int q = tid; q < nq; q += 256) {
        int4 r = r4[q];
        int4 c = c4[q];
        atomicAdd(&hw[r.x >> BSHIFT], 1); atomicAdd(&hw[c.x >> BSHIFT], 1);
        atomicAdd(&hw[r.y >> BSHIFT], 1); atomicAdd(&hw[c.y >> BSHIFT], 1);
        atomicAdd(&hw[r.z >> BSHIFT], 1); atomicAdd(&hw[c.z >> BSHIFT], 1);
        atomicAdd(&hw[r.w >> BSHIFT], 1); atomicAdd(&hw[c.w >> BSHIFT], 1);
    }
    __syncthreads();
    // B: bucket totals -> 512-wide exclusive scan -> reserve global runs.
    for (int i = tid; i < 512; i += 256)
        sA[i] = (i < NB) ? (h[i] + h[NB + i] + h[2 * NB + i] + h[3 * NB + i]) : 0;
    __syncthreads();
    int* c_ = sA; int* n_ = sB;
    for (int off = 1; off < 512; off <<= 1) {
        for (int i = tid; i < 512; i += 256)
            n_[i] = (i >= off) ? c_[i] + c_[i - off] : c_[i];
        __syncthreads();
        int* t = c_; c_ = n_; n_ = t;
    }
    for (int i = tid; i < NB; i += 256) {
        int tot = h[i] + h[NB + i] + h[2 * NB + i] + h[3 * NB + i];
        int excl = c_[i] - tot;
        lo[i] = excl;
        lc[i] = excl;
        int base = i << CAPSHIFT;
        if (tot) base += atomicAdd(&cursor[i], tot);   // reserve run
        gb[i] = base;
    }
    __syncthreads();
    // C: scatter into bucket-sorted staging with precomputed global addr.
    for (int q = tid; q < nq; q += 256) {
        int4 r = r4[q];
        int4 c = c4[q];
        int rr[4] = { r.x, r.y, r.z, r.w };
        int cc[4] = { c.x, c.y, c.z, c.w };
#pragma unroll
        for (int j = 0; j < 4; ++j) {
            int b1 = cc[j] >> BSHIFT;
            int p1 = atomicAdd(&lc[b1], 1);
            stage[p1] = make_int2(gb[b1] + (p1 - lo[b1]),
                                  ((cc[j] & (BUCKET - 1)) << 18) | rr[j]);
            int b2 = rr[j] >> BSHIFT;
            int p2 = atomicAdd(&lc[b2], 1);
            stage[p2] = make_int2(gb[b2] + (p2 - lo[b2]),
                                  ((rr[j] & (BUCKET - 1)) << 18) | cc[j]);
        }
    }
    __syncthreads();
    // D: coalesced drain (consecutive threads -> consecutive addrs per run).
    int totAll = 2 * (e1 - e0);
    for (int s = tid; s < totAll; s += 256) {
        int2 v = stage[s];
        binned[v.x] = v.y;
    }
}

// --- Per-bucket padded CSR -------------------------------------------------
// Node segments padded to multiple of 4; pad slots = N_NODES (zero row).
// nodeinfo = {start, deg, bits(1/sqrt(da)), bits(sqrt(da))}.
__global__ void __launch_bounds__(BUCKET)
lgcn_build_csr(const int* __restrict__ cursor, const int* __restrict__ binned,
               int4* __restrict__ nodeinfo, int* __restrict__ packed) {
    __shared__ int hist[BUCKET], sA[BUCKET], sB[BUCKET], cur[BUCKET];
    int b = blockIdx.x;
    int tid = threadIdx.x;
    hist[tid] = 0;
    __syncthreads();
    int e0 = b << CAPSHIFT;
    int e1 = e0 + cursor[b];                   // bucket edge count
    for (int j = e0 + tid; j < e1; j += BUCKET)
        atomicAdd(&hist[binned[j] >> 18], 1);
    __syncthreads();
    int deg = hist[tid];
    int degp = (deg + 3) & ~3;                 // padded segment length
    sA[tid] = degp;
    __syncthreads();
    int* c_ = sA; int* n_ = sB;
    for (int off = 1; off < BUCKET; off <<= 1) {
        n_[tid] = (tid >= off) ? c_[tid] + c_[tid - off] : c_[tid];
        __syncthreads();
        int* t = c_; c_ = n_; n_ = t;
    }
    int start = e0 + (c_[tid] - degp);         // exclusive scan, int4-aligned
    cur[tid] = start;
    int node = (b << BSHIFT) + tid;
    if (node < N_NODES) {
        float da = (deg == 0) ? 1.0f : (float)deg;
        float sq = sqrtf(da);
        int4 ni;
        ni.x = start;
        ni.y = deg;
        ni.z = __float_as_int(1.0f / sq);
        ni.w = __float_as_int(sq);
        nodeinfo[node] = ni;
    }
    __syncthreads();
    for (int j = e0 + tid; j < e1; j += BUCKET) {
        int w = binned[j];
        int pos = atomicAdd(&cur[w >> 18], 1); // LDS atomic
        packed[pos] = w & 0x3FFFF;             // src only
    }
    // Pad slots -> zero row (disjoint targets; no sync needed).
    for (int kk = deg; kk < degp; ++kk)
        packed[start + kk] = N_NODES;
}

// --- Propagation -----------------------------------------------------------

// g0[n] = norm[n] * x[n]  (bf16), plus zero row N_NODES in BOTH buffers.
__global__ void lgcn_init_g0(const float* __restrict__ ue, const float* __restrict__ ie,
                             const int4* __restrict__ nodeinfo,
                             bf16_t* __restrict__ g0, bf16_t* __restrict__ g1) {
    int t = blockIdx.x * blockDim.x + threadIdx.x;     // ushort4-chunk slot
    const int nT = N_NODES * (DIM / 4);
    if (t >= nT) {
        if (t < nT + 16)
            ((ushort4*)g0)[nT + (t - nT)] = make_ushort4(0, 0, 0, 0);
        else if (t < nT + 32)
            ((ushort4*)g1)[nT + (t - nT - 16)] = make_ushort4(0, 0, 0, 0);
        return;
    }
    int n = t >> 4;
    const int nU = N_USERS * (DIM / 4);
    float4 x = (t < nU) ? ((const float4*)ue)[t] : ((const float4*)ie)[t - nU];
    float nm = __int_as_float(nodeinfo[n].z);
    ushort4 o;
    o.x = f2bf(x.x * nm); o.y = f2bf(x.y * nm);
    o.z = f2bf(x.z * nm); o.w = f2bf(x.w * nm);
    ((ushort4*)g0)[t] = o;
}

// Gather core: 16-lane group sums g rows for edges [start, start+deg).
// Pad slots point at the zero row -> plain adds, no clamps, no weights.
static __device__ __forceinline__ float4
gather_sum(const bf16_t* __restrict__ g, const int* __restrict__ packed,
           int start, int deg, int grp, int c) {
    float4 acc = make_float4(0.f, 0.f, 0.f, 0.f);
    for (int o = 4 * grp; o < deg; o += 16) {
        int4 e4 = *(const int4*)(packed + start + o);  // 16-B aligned
        ushort4 v0 = ((const ushort4*)(g + (size_t)e4.x * DIM))[c];
        ushort4 v1 = ((const ushort4*)(g + (size_t)e4.y * DIM))[c];
        ushort4 v2 = ((const ushort4*)(g + (size_t)e4.z * DIM))[c];
        ushort4 v3 = ((const ushort4*)(g + (size_t)e4.w * DIM))[c];
        acc.x += bf2f(v0.x); acc.y += bf2f(v0.y);
        acc.z += bf2f(v0.z); acc.w += bf2f(v0.w);
        acc.x += bf2f(v1.x); acc.y += bf2f(v1.y);
        acc.z += bf2f(v1.z); acc.w += bf2f(v1.w);
        acc.x += bf2f(v2.x); acc.y += bf2f(v2.y);
        acc.z += bf2f(v2.z); acc.w += bf2f(v2.w);
        acc.x += bf2f(v3.x); acc.y += bf2f(v3.y);
        acc.z += bf2f(v3.z); acc.w += bf2f(v3.w);
    }
    return acc;
}

// Full pull (round-7 form): one wave per node, 4 nodes per block.
// gn[n] = bf16( norm[n]^2 * sum_{s in N(n)} g[s] ).
__global__ void __launch_bounds__(256)
lgcn_pull(const bf16_t* __restrict__ g, const int4* __restrict__ nodeinfo,
          const int* __restrict__ packed, bf16_t* __restrict__ gn) {
    int n = blockIdx.x * 4 + (threadIdx.x >> 6);
    if (n >= N_NODES) return;
    int lane = threadIdx.x & 63;
    int grp = lane >> 4;
    int c = lane & 15;
    int4 ni = nodeinfo[n];
    float4 acc = gather_sum(g, packed, ni.x, ni.y, grp, c);
#pragma unroll
    for (int off = 16; off < 64; off <<= 1) {
        acc.x += __shfl_xor(acc.x, off, 64);
        acc.y += __shfl_xor(acc.y, off, 64);
        acc.z += __shfl_xor(acc.z, off, 64);
        acc.w += __shfl_xor(acc.w, off, 64);
    }
    if (lane < 16) {
        float nm = __int_as_float(ni.z);
        float s2 = nm * nm;
        ushort4 o;
        o.x = f2bf(acc.x * s2); o.y = f2bf(acc.y * s2);
        o.z = f2bf(acc.z * s2); o.w = f2bf(acc.w * s2);
        ((ushort4*)(gn + (size_t)n * DIM))[c] = o;
    }
}

// Fused layer-3 + epilogue, batch nodes only:
// out[slot] = 0.25*( x[n] + rn*g1[n] + rn*g2[n] + nm*sum_{s in N(n)} g2[s] ).
__global__ void __launch_bounds__(256)
lgcn_final(const float* __restrict__ ue, const float* __restrict__ ie,
           const bf16_t* __restrict__ g1, const bf16_t* __restrict__ g2,
           const int4* __restrict__ nodeinfo, const int* __restrict__ packed,
           const int* __restrict__ uid, const int* __restrict__ iid,
           float* __restrict__ out) {
    int slot = blockIdx.x * 4 + (threadIdx.x >> 6);
    if (slot >= 2 * BATCH) return;
    int lane = threadIdx.x & 63;
    int grp = lane >> 4;
    int c = lane & 15;
    int isItem = slot >= BATCH;
    int b = isItem ? (slot - BATCH) : slot;
    int node = isItem ? (N_USERS + iid[b]) : uid[b];
    int4 ni = nodeinfo[node];
    float4 acc = gather_sum(g2, packed, ni.x, ni.y, grp, c);
#pragma unroll
    for (int off = 16; off < 64; off <<= 1) {
        acc.x += __shfl_xor(acc.x, off, 64);
        acc.y += __shfl_xor(acc.y, off, 64);
        acc.z += __shfl_xor(acc.z, off, 64);
        acc.w += __shfl_xor(acc.w, off, 64);
    }
    if (lane < 16) {
        const float* xb = isItem ? (ie + (size_t)(node - N_USERS) * DIM)
                                 : (ue + (size_t)node * DIM);
        float4 x = ((const float4*)xb)[c];
        ushort4 a1 = ((const ushort4*)(g1 + (size_t)node * DIM))[c];
        ushort4 a2 = ((const ushort4*)(g2 + (size_t)node * DIM))[c];
        float rn = __int_as_float(ni.w);
        float nm = __int_as_float(ni.z);
        float4 r;
        r.x = 0.25f * (x.x + rn * (bf2f(a1.x) + bf2f(a2.x)) + nm * acc.x);
        r.y = 0.25f * (x.y + rn * (bf2f(a1.y) + bf2f(a2.y)) + nm * acc.y);
        r.z = 0.25f * (x.z + rn * (bf2f(a1.z) + bf2f(a2.z)) + nm * acc.z);
        r.w = 0.25f * (x.w + rn * (bf2f(a1.w) + bf2f(a2.w)) + nm * acc.w);
        ((float4*)(out + (size_t)slot * DIM))[c] = r;
    }
}

// --- Launch ----------------------------------------------------------------

extern "C" void kernel_launch(void* const* d_in, const int* in_sizes, int n_in,
                              void* d_out, int out_size, void* d_ws, size_t ws_size,
                              hipStream_t stream) {
    const float* ue  = (const float*)d_in[0];
    const float* ie  = (const float*)d_in[1];
    const int*   ei  = (const int*)d_in[3];
    const int*   uid = (const int*)d_in[4];
    const int*   iid = (const int*)d_in[5];
    float* out = (float*)d_out;

    const int E  = in_sizes[2];     // 2,000,000 directed edges
    const int EH = E / 2;           // 1,000,000 undirected pairs
    const int* row = ei;            // first-half src = user ids
    const int* col = ei + E;        // first-half dst = item node ids

    const int NB1 = (EH + PAIRS_PER_BLK - 1) / PAIRS_PER_BLK;   // 489

    // Workspace carve-up (256-B aligned), ~80 MB total.
    char* p = (char*)d_ws;
    size_t off = 0;
    auto carve = [&](size_t bytes) -> char* {
        char* r = p + off;
        off += (bytes + 255) & ~(size_t)255;
        return r;
    };
    const size_t nodeBf16 = (size_t)(N_NODES + 1) * DIM * sizeof(bf16_t); // +zero row
    bf16_t* gA       = (bf16_t*)carve(nodeBf16);
    bf16_t* gB       = (bf16_t*)carve(nodeBf16);
    int4*   nodeinfo = (int4*)carve((size_t)N_NODES * sizeof(int4));     // 2.4 MB
    int*    cursor   = (int*)carve((size_t)NB * sizeof(int));
    int*    binned   = (int*)carve((size_t)NB * CAP * sizeof(int));      // 19.2 MB
    int*    packed   = (int*)carve((size_t)NB * CAP * sizeof(int));      // 19.2 MB
    (void)ws_size;

    // 1) Binning (cursor must start at zero) + per-bucket CSR.
    hipMemsetAsync(cursor, 0, (size_t)NB * sizeof(int), stream);
    lgcn_bin<<<NB1, 256, 0, stream>>>(row, col, cursor, binned, EH);
    lgcn_build_csr<<<NB, BUCKET, 0, stream>>>(cursor, binned, nodeinfo, packed);

    // 2) g0 = norm*x (bf16) + zero rows in both buffers.
    lgcn_init_g0<<<(N_NODES * (DIM / 4) + 32 + 255) / 256, 256, 0, stream>>>(
        ue, ie, nodeinfo, gA, gB);

    // 3) Two full pulls (g1, g2), then fused batch-only layer 3 + epilogue.
    const int pullGrid = (N_NODES + 3) / 4;
    lgcn_pull<<<pullGrid, 256, 0, stream>>>(gA, nodeinfo, packed, gB);  // g1 = gB
    lgcn_pull<<<pullGrid, 256, 0, stream>>>(gB, nodeinfo, packed, gA);  // g2 = gA
    lgcn_final<<<(2 * BATCH + 3) / 4, 256, 0, stream>>>(
        ue, ie, gB, gA, nodeinfo, packed, uid, iid, out);
}